// Round 20
// baseline (206.905 us; speedup 1.0000x reference)
//
#include <hip/hip_runtime.h>
#include <hip/hip_bf16.h>
#include <math.h>

// Problem: CausalSelfAttention  B=4 T=2048 D=1024 H=16 HD=64
// d_in: fp32 x[4,2048,1024], Wq,Wk,Wv,Wp[1024,1024], bp[1024]; d_out: fp32 y.
// Pipeline: cvt_all(fp32->bf16) -> qkv -> attn -> proj.
// V stored TRANSPOSED [B,H,HD,T]. attn = 32x32-MFMA body (verified r16).
// qkv v3: 256x128 tile, 8 waves / 512 threads; per-wave resources identical
// to the verified 128x128 body (acc[4][4], ~96 VGPR) -> no spill risk;
// staged bytes per MFMA -25%; grid 32x24=768 = exactly 3 blocks/CU.
// !! LAUNCH-BOUNDS TRAP (r17/r18): second arg w caps VGPR at 512/w per wave;
// (256,4)=64-cap spilled acc. (512,2)=256-cap is safe. qkv/proj keep caps
// >= 128.

#define B_  4
#define T_  2048
#define D_  1024
#define H_  16
#define HD_ 64
#define M_  (B_ * T_)   // 8192 rows

typedef short bf16x8 __attribute__((ext_vector_type(8)));
typedef float f32x4  __attribute__((ext_vector_type(4)));
typedef float f32x16 __attribute__((ext_vector_type(16)));

__device__ __forceinline__ f32x4 mfma16(bf16x8 a, bf16x8 b, f32x4 c) {
    return __builtin_amdgcn_mfma_f32_16x16x32_bf16(a, b, c, 0, 0, 0);
}
__device__ __forceinline__ f32x16 mfma32(bf16x8 a, bf16x8 b, f32x16 c) {
    return __builtin_amdgcn_mfma_f32_32x32x16_bf16(a, b, c, 0, 0, 0);
}

__device__ __forceinline__ void gl_lds16(const unsigned short* g, unsigned short* l) {
    __builtin_amdgcn_global_load_lds(
        (const __attribute__((address_space(1))) void*)g,
        (__attribute__((address_space(3))) void*)l, 16, 0, 0);
}

__device__ __forceinline__ unsigned short f2bf(float f) {
    union { __hip_bfloat16 h; unsigned short u; } cv;
    cv.h = __float2bfloat16(f);
    return cv.u;
}
__device__ __forceinline__ float bf2f(unsigned short u) {
    return __uint_as_float(((unsigned)u) << 16);
}
__device__ __forceinline__ float exp2_fast(float x) {
    return __builtin_amdgcn_exp2f(x);   // v_exp_f32: 2^x
}

struct su4 { unsigned short x, y, z, w; };

// ---------------------------------------------------------------------------
// Single fp32->bf16 conversion kernel for x + all 4 weights.
// ---------------------------------------------------------------------------
__global__ __launch_bounds__(256)
void cvt_all_kernel(const float* __restrict__ x,
                    const float* __restrict__ Wq, const float* __restrict__ Wk,
                    const float* __restrict__ Wv, const float* __restrict__ Wp,
                    unsigned short* __restrict__ dst) {
    const int i = blockIdx.x * 256 + threadIdx.x;   // float4 index, < 3145728
    const float* src;
    int j;
    if (i < 2097152) {                              // x: 8388608 elems / 4
        src = x; j = i;
    } else {
        const int k = i - 2097152;
        const int wsel = k >> 18;                   // 262144 float4 per weight
        j = k & 262143;
        src = (wsel == 0) ? Wq : (wsel == 1) ? Wk : (wsel == 2) ? Wv : Wp;
    }
    const float4 v = ((const float4*)src)[j];
    su4 o;
    o.x = f2bf(v.x); o.y = f2bf(v.y); o.z = f2bf(v.z); o.w = f2bf(v.w);
    ((su4*)dst)[i] = o;
}

// ---------------------------------------------------------------------------
// Fused QKV GEMM v3: 256x128 tile, 8 waves.  C = X @ W^T.  Q,K -> [B,H,T,HD];
// V -> [B,H,HD,T] via operand-swapped MFMA.  Epilogue: per instruction,
// 16 lanes write 16 contiguous 2B values (32B segments) - coalesced.
// ---------------------------------------------------------------------------
__global__ __launch_bounds__(512, 2)
void qkv_kernel(const unsigned short* __restrict__ X,
                const unsigned short* __restrict__ Wq,
                const unsigned short* __restrict__ Wk,
                const unsigned short* __restrict__ Wv,
                unsigned short* __restrict__ Qo,
                unsigned short* __restrict__ Ko,
                unsigned short* __restrict__ Vo)
{
    __shared__ unsigned short As[256 * 64];   // 32KB
    __shared__ unsigned short Bs[128 * 64];   // 16KB

    const int m0 = blockIdx.x * 256;
    const int by = blockIdx.y;
    const unsigned short* W = (by < 8) ? Wq : (by < 16) ? Wk : Wv;
    unsigned short*       O = (by < 8) ? Qo : (by < 16) ? Ko : Vo;
    const int n0   = (by & 7) * 128;
    const bool vsec = (by >= 16);
    const int tid  = threadIdx.x;             // 0..511
    const int lane = tid & 63;
    const int wv   = tid >> 6;                // wave 0..7
    const int wr   = (wv >> 1) * 64;          // 0,64,128,192
    const int wc   = (wv & 1) * 64;           // 0,64
    const int g    = lane >> 4;
    const int c    = lane & 15;

    f32x4 acc[4][4] = {};

    for (int k0 = 0; k0 < D_; k0 += 64) {
        #pragma unroll
        for (int i = 0; i < 4; ++i) {         // A: 32KB = 4 x 512 x 16B
            const int flat = i * 4096 + tid * 8;
            const int row = flat >> 6, col = flat & 63;
            gl_lds16(X + (size_t)(m0 + row) * D_ + k0 + col, As + flat);
        }
        #pragma unroll
        for (int i = 0; i < 2; ++i) {         // B: 16KB = 2 x 512 x 16B
            const int flat = i * 4096 + tid * 8;
            const int row = flat >> 6, col = flat & 63;
            gl_lds16(W + (size_t)(n0 + row) * D_ + k0 + col, Bs + flat);
        }
        __syncthreads();
        #pragma unroll
        for (int kk = 0; kk < 64; kk += 32) {
            bf16x8 af[4], bg[4];
            #pragma unroll
            for (int mi = 0; mi < 4; ++mi)
                af[mi] = *(const bf16x8*)(As + (wr + mi * 16 + c) * 64 + kk + g * 8);
            #pragma unroll
            for (int ni = 0; ni < 4; ++ni)
                bg[ni] = *(const bf16x8*)(Bs + (wc + ni * 16 + c) * 64 + kk + g * 8);
            if (!vsec) {
                #pragma unroll
                for (int mi = 0; mi < 4; ++mi)
                    #pragma unroll
                    for (int ni = 0; ni < 4; ++ni)
                        acc[mi][ni] = mfma16(af[mi], bg[ni], acc[mi][ni]);
            } else {
                #pragma unroll
                for (int mi = 0; mi < 4; ++mi)
                    #pragma unroll
                    for (int ni = 0; ni < 4; ++ni)
                        acc[mi][ni] = mfma16(bg[ni], af[mi], acc[mi][ni]);
            }
        }
        __syncthreads();
    }

    if (!vsec) {
        #pragma unroll
        for (int mi = 0; mi < 4; ++mi)
            #pragma unroll
            for (int ni = 0; ni < 4; ++ni)
                #pragma unroll
                for (int r = 0; r < 4; ++r) {
                    const int m = m0 + wr + mi * 16 + g * 4 + r;
                    const int n = n0 + wc + ni * 16 + c;
                    const int b = m >> 11, t = m & (T_ - 1);
                    const int h = n >> 6,  hd = n & 63;
                    O[((size_t)((b << 4) + h) * T_ + t) * HD_ + hd] = f2bf(acc[mi][ni][r]);
                }
    } else {
        #pragma unroll
        for (int mi = 0; mi < 4; ++mi)
            #pragma unroll
            for (int ni = 0; ni < 4; ++ni)
                #pragma unroll
                for (int r = 0; r < 4; ++r) {
                    const int n = n0 + wc + ni * 16 + g * 4 + r;
                    const int m = m0 + wr + mi * 16 + c;
                    const int b = m >> 11, t = m & (T_ - 1);
                    const int h = n >> 6,  hd = n & 63;
                    O[((size_t)((b << 4) + h) * HD_ + hd) * T_ + t] = f2bf(acc[mi][ni][r]);
                }
    }
}

// ---------------------------------------------------------------------------
// Causal flash attention (r16 verified): 32x32 MFMA, 4 waves x 32 q-rows =
// 128 rows per block.  Grid (64 bh, 16 q-tiles) LPT.  Double-buffered LDS,
// 3-bit XOR swizzle, defer-max, setprio.
// ---------------------------------------------------------------------------
__global__ __launch_bounds__(256, 4)
void attn_kernel(const unsigned short* __restrict__ Q,
                 const unsigned short* __restrict__ K,
                 const unsigned short* __restrict__ VT,
                 unsigned short* __restrict__ Y)
{
    __shared__ unsigned short Ks[2][4096];   // K tiles, swizzled
    __shared__ unsigned short Vs[2][4096];   // V^T tiles, swizzled

    const int bh = blockIdx.x;          // fast axis -> XCD panel residency
    const int qt = 15 - blockIdx.y;     // LPT: heaviest q-tiles first
    const unsigned short* Qp  = Q  + (size_t)bh * T_ * HD_;
    const unsigned short* Kp  = K  + (size_t)bh * T_ * HD_;
    const unsigned short* VTp = VT + (size_t)bh * HD_ * T_;
    const int b = bh >> 4, h = bh & 15;

    const int tid  = threadIdx.x;
    const int lane = tid & 63;
    const int w    = tid >> 6;          // wave 0..3
    const int hi   = lane >> 5;         // lane half
    const int q31  = lane & 31;
    const float SC = 0.18033688011112042f;   // (1/sqrt(64)) * log2(e)

    const int qw = qt * 128 + w * 32;   // wave's q base (32 rows)
    const int nt = 2 * qt + 2;          // 64-key tiles (even)

    // Staging constants (3-bit swizzle involution)
    int srow[2], scol[2];
    #pragma unroll
    for (int i = 0; i < 2; ++i) {
        const int L = (i * 256 + tid) * 16;
        srow[i] = L >> 7;                                   // 0..63
        scol[i] = (L & 127) ^ ((srow[i] & 7) << 4);         // pre-swizzled src col (bytes)
    }

    // Q as B-operand frags: col q = q31, k(d) = dstep*16 + hi*8 + j; pre-scaled
    bf16x8 qf[4];
    #pragma unroll
    for (int dstep = 0; dstep < 4; ++dstep) {
        bf16x8 t = *(const bf16x8*)(Qp + (size_t)(qw + q31) * HD_ + dstep * 16 + hi * 8);
        #pragma unroll
        for (int j = 0; j < 8; ++j)
            t[j] = (short)f2bf(bf2f((unsigned short)t[j]) * SC);
        qf[dstep] = t;
    }

    float m_l = -1e30f, l_l = 0.f;
    f32x16 o0 = {}, o1 = {};            // O^T: d-halves 0..31 / 32..63, col q
    const int swz = (lane & 7) << 4;    // read swizzle (read rows ≡ lane&7 mod 8)

    auto stage = [&](int buf, int tb) {
        #pragma unroll
        for (int i = 0; i < 2; ++i) {
            const int L = (i * 256 + tid) * 16;
            gl_lds16(Kp + (size_t)(tb + srow[i]) * HD_ + (scol[i] >> 1),
                     &Ks[buf][L >> 1]);
            gl_lds16(VTp + (size_t)srow[i] * T_ + tb + (scol[i] >> 1),
                     &Vs[buf][L >> 1]);
        }
    };

    auto compute = [&](const unsigned short* Kbuf, const unsigned short* Vbuf, int tb) {
        if (tb > qw + 31) return;       // wave fully masked
        const char* Kb = (const char*)Kbuf;
        const char* Vb = (const char*)Vbuf;

        __builtin_amdgcn_s_setprio(1);

        // ---- QK^T (swapped): s0 = keys tb..tb+31, s1 = tb+32..tb+63
        f32x16 s0 = {}, s1 = {};
        #pragma unroll
        for (int dstep = 0; dstep < 4; ++dstep) {
            const int col = (dstep * 32 + hi * 16) ^ swz;
            const bf16x8 kA = *(const bf16x8*)(Kb + q31 * 128 + col);
            const bf16x8 kB = *(const bf16x8*)(Kb + (32 + q31) * 128 + col);
            s0 = mfma32(kA, qf[dstep], s0);
            s1 = mfma32(kB, qf[dstep], s1);
        }

        // ---- causal mask (diagonal zone): key row = (r&3)+8*(r>>2)+4*hi
        if (tb + 63 > qw) {
            const int qq = qw + q31;
            #pragma unroll
            for (int r = 0; r < 16; ++r) {
                const int key = tb + (r & 3) + 8 * (r >> 2) + 4 * hi;
                s0[r] = (key      <= qq) ? s0[r] : -1e30f;
                s1[r] = (key + 32 <= qq) ? s1[r] : -1e30f;
            }
        }

        // ---- online softmax: per-lane 32 vals (one q) + 1 shuffle
        float pmax = s0[0];
        #pragma unroll
        for (int r = 1; r < 16; ++r) pmax = fmaxf(pmax, s0[r]);
        #pragma unroll
        for (int r = 0; r < 16; ++r) pmax = fmaxf(pmax, s1[r]);
        pmax = fmaxf(pmax, __shfl_xor(pmax, 32));

        const bool skip = __all(pmax - m_l <= 8.0f);
        float al = 1.f;
        if (!skip) {
            const float mn = fmaxf(m_l, pmax);
            al = exp2_fast(m_l - mn);
            m_l = mn;
        }

        float rs = 0.f;
        #pragma unroll
        for (int r = 0; r < 16; ++r) {
            const float e0 = exp2_fast(s0[r] - m_l);
            const float e1 = exp2_fast(s1[r] - m_l);
            s0[r] = e0; s1[r] = e1;
            rs += e0 + e1;
        }
        rs += __shfl_xor(rs, 32);
        l_l = l_l * al + rs;

        // ---- pack P into 4-reg groups (2 u32 each), exchange lane<->lane+32
        unsigned Glo0[4], Ghi0[4], Glo1[4], Ghi1[4];
        #pragma unroll
        for (int m = 0; m < 4; ++m) {
            Glo0[m] = (unsigned)f2bf(s0[4*m])   | ((unsigned)f2bf(s0[4*m+1]) << 16);
            Ghi0[m] = (unsigned)f2bf(s0[4*m+2]) | ((unsigned)f2bf(s0[4*m+3]) << 16);
            Glo1[m] = (unsigned)f2bf(s1[4*m])   | ((unsigned)f2bf(s1[4*m+1]) << 16);
            Ghi1[m] = (unsigned)f2bf(s1[4*m+2]) | ((unsigned)f2bf(s1[4*m+3]) << 16);
        }
        unsigned PGlo0[4], PGhi0[4], PGlo1[4], PGhi1[4];
        #pragma unroll
        for (int m = 0; m < 4; ++m) {
            PGlo0[m] = (unsigned)__shfl_xor((int)Glo0[m], 32);
            PGhi0[m] = (unsigned)__shfl_xor((int)Ghi0[m], 32);
            PGlo1[m] = (unsigned)__shfl_xor((int)Glo1[m], 32);
            PGhi1[m] = (unsigned)__shfl_xor((int)Ghi1[m], 32);
        }

        // ---- assemble PV B-frags: pf[ks], k = ks*16 + hi*8 + j
        bf16x8 pf[4];
        #pragma unroll
        for (int ks = 0; ks < 4; ++ks) {
            const int m0i = 2 * (ks & 1);
            const int m1i = m0i + 1;
            const unsigned gl0 = (ks < 2) ? Glo0[m0i] : Glo1[m0i];
            const unsigned gh0 = (ks < 2) ? Ghi0[m0i] : Ghi1[m0i];
            const unsigned gl1 = (ks < 2) ? Glo0[m1i] : Glo1[m1i];
            const unsigned gh1 = (ks < 2) ? Ghi0[m1i] : Ghi1[m1i];
            const unsigned pl0 = (ks < 2) ? PGlo0[m0i] : PGlo1[m0i];
            const unsigned ph0 = (ks < 2) ? PGhi0[m0i] : PGhi1[m0i];
            const unsigned pl1 = (ks < 2) ? PGlo0[m1i] : PGlo1[m1i];
            const unsigned ph1 = (ks < 2) ? PGhi0[m1i] : PGhi1[m1i];
            union { unsigned u[4]; bf16x8 v; } pp;
            pp.u[0] = hi ? pl1 : gl0;
            pp.u[1] = hi ? ph1 : gh0;
            pp.u[2] = hi ? gl1 : pl0;
            pp.u[3] = hi ? gh1 : ph0;
            pf[ks] = pp.v;
        }

        // ---- rescale (skipped when deferred) + PV
        if (!skip) {
            #pragma unroll
            for (int r = 0; r < 16; ++r) { o0[r] *= al; o1[r] *= al; }
        }
        #pragma unroll
        for (int ks = 0; ks < 4; ++ks) {
            const int col = (ks * 32 + hi * 16) ^ swz;
            const bf16x8 vA = *(const bf16x8*)(Vb + q31 * 128 + col);
            const bf16x8 vB = *(const bf16x8*)(Vb + (32 + q31) * 128 + col);
            o0 = mfma32(vA, pf[ks], o0);
            o1 = mfma32(vB, pf[ks], o1);
        }

        __builtin_amdgcn_s_setprio(0);
    };

    // 2x double-buffer pipeline (nt even)
    stage(0, 0);
    __syncthreads();
    for (int ti = 0; ti < nt; ti += 2) {
        stage(1, (ti + 1) << 6);
        compute(Ks[0], Vs[0], ti << 6);
        __syncthreads();
        if (ti + 2 < nt) stage(0, (ti + 2) << 6);
        compute(Ks[1], Vs[1], (ti + 1) << 6);
        __syncthreads();
    }

    // ---- epilogue: O[q = qw+q31][d = dhalf*32 + 8t + 4hi + e], uint2 stores
    const float li = 1.f / l_l;
    const size_t rowoff = (size_t)(b * T_ + qw + q31) * D_ + h * 64;
    #pragma unroll
    for (int t = 0; t < 4; ++t) {
        uint2 st0, st1;
        st0.x = (unsigned)f2bf(o0[4*t]   * li) | ((unsigned)f2bf(o0[4*t+1] * li) << 16);
        st0.y = (unsigned)f2bf(o0[4*t+2] * li) | ((unsigned)f2bf(o0[4*t+3] * li) << 16);
        st1.x = (unsigned)f2bf(o1[4*t]   * li) | ((unsigned)f2bf(o1[4*t+1] * li) << 16);
        st1.y = (unsigned)f2bf(o1[4*t+2] * li) | ((unsigned)f2bf(o1[4*t+3] * li) << 16);
        *(uint2*)(Y + rowoff      + 8 * t + 4 * hi) = st0;
        *(uint2*)(Y + rowoff + 32 + 8 * t + 4 * hi) = st1;
    }
}

// ---------------------------------------------------------------------------
// Output projection:  out = Y @ Wp^T + bp.  Y bf16[8192,1024]; out fp32.
// KEEP (256,2): (256,4) would cap VGPR at 64 -> spill (r17/r18 trap).
// ---------------------------------------------------------------------------
__global__ __launch_bounds__(256, 2)
void proj_kernel(const unsigned short* __restrict__ Yin,
                 const unsigned short* __restrict__ Wp,
                 const float* __restrict__ bp,
                 float* __restrict__ Out)
{
    __shared__ unsigned short As[128 * 64];
    __shared__ unsigned short Bs[128 * 64];

    const int m0 = blockIdx.x * 128;
    const int n0 = blockIdx.y * 128;
    const int tid  = threadIdx.x;
    const int lane = tid & 63;
    const int wv   = tid >> 6;
    const int wr   = (wv >> 1) * 64;
    const int wc   = (wv & 1) * 64;
    const int g    = lane >> 4;
    const int c    = lane & 15;

    f32x4 acc[4][4] = {};

    for (int k0 = 0; k0 < D_; k0 += 64) {
        #pragma unroll
        for (int i = 0; i < 4; ++i) {
            const int flat = i * 2048 + tid * 8;
            const int row = flat >> 6, col = flat & 63;
            gl_lds16(Yin + (size_t)(m0 + row) * D_ + k0 + col, As + flat);
            gl_lds16(Wp  + (size_t)(n0 + row) * D_ + k0 + col, Bs + flat);
        }
        __syncthreads();
        #pragma unroll
        for (int kk = 0; kk < 64; kk += 32) {
            bf16x8 af[4], bg[4];
            #pragma unroll
            for (int mi = 0; mi < 4; ++mi)
                af[mi] = *(const bf16x8*)(As + (wr + mi * 16 + c) * 64 + kk + g * 8);
            #pragma unroll
            for (int ni = 0; ni < 4; ++ni)
                bg[ni] = *(const bf16x8*)(Bs + (wc + ni * 16 + c) * 64 + kk + g * 8);
            #pragma unroll
            for (int mi = 0; mi < 4; ++mi)
                #pragma unroll
                for (int ni = 0; ni < 4; ++ni)
                    acc[mi][ni] = mfma16(af[mi], bg[ni], acc[mi][ni]);
        }
        __syncthreads();
    }

    #pragma unroll
    for (int mi = 0; mi < 4; ++mi) {
        #pragma unroll
        for (int ni = 0; ni < 4; ++ni) {
            const int n = n0 + wc + ni * 16 + c;
            const float bb = bp[n];
            #pragma unroll
            for (int r = 0; r < 4; ++r) {
                const int m = m0 + wr + mi * 16 + g * 4 + r;
                Out[(size_t)m * D_ + n] = acc[mi][ni][r] + bb;
            }
        }
    }
}

// ---------------------------------------------------------------------------
extern "C" void kernel_launch(void* const* d_in, const int* in_sizes, int n_in,
                              void* d_out, int out_size, void* d_ws, size_t ws_size,
                              hipStream_t stream) {
    const float* x  = (const float*)d_in[0];
    const float* Wq = (const float*)d_in[1];
    const float* Wk = (const float*)d_in[2];
    const float* Wv = (const float*)d_in[3];
    const float* Wp = (const float*)d_in[4];
    const float* bp = (const float*)d_in[5];
    float* out = (float*)d_out;

    const size_t SZ  = (size_t)M_ * D_;      // 8388608
    const size_t WSZ = (size_t)D_ * D_;      // 1048576
    unsigned short* ws = (unsigned short*)d_ws;
    unsigned short* XB  = ws;                 // also Y after qkv
    unsigned short* WQB = XB  + SZ;
    unsigned short* WKB = WQB + WSZ;
    unsigned short* WVB = WKB + WSZ;
    unsigned short* WPB = WVB + WSZ;
    unsigned short* Qw  = WPB + WSZ;
    unsigned short* Kw  = Qw + SZ;
    unsigned short* Vw  = Kw + SZ;            // V^T [B,H,HD,T]
    unsigned short* Yw  = XB;                 // overlay: x_bf16 dead after qkv

    dim3 blk(256);
    cvt_all_kernel<<<dim3(12288), blk, 0, stream>>>(x, Wq, Wk, Wv, Wp, ws);

    qkv_kernel <<<dim3(M_ / 256, 24), dim3(512), 0, stream>>>(XB, WQB, WKB, WVB, Qw, Kw, Vw);
    attn_kernel<<<dim3(B_ * H_, 16), blk, 0, stream>>>(Qw, Kw, Vw, Yw);
    proj_kernel<<<dim3(M_ / 128, D_ / 128), blk, 0, stream>>>(Yw, WPB, bp, out);
}

// Round 21
// 179.891 us; speedup vs baseline: 1.1502x; 1.1502x over previous
//
#include <hip/hip_runtime.h>
#include <hip/hip_bf16.h>
#include <math.h>

// Problem: CausalSelfAttention  B=4 T=2048 D=1024 H=16 HD=64
// d_in: fp32 x[4,2048,1024], Wq,Wk,Wv,Wp[1024,1024], bp[1024]; d_out: fp32 y.
// Pipeline: cvt_all(fp32->bf16) -> qkv -> attn -> proj.   (r19 verified build)
// V stored TRANSPOSED [B,H,HD,T]. attn = 32x32-MFMA body (verified r16).
// !! LAUNCH-BOUNDS TRAP: __launch_bounds__ second arg w caps VGPR at 512/w;
// (256,4) = 64-VGPR cap spills qkv/proj acc[4][4] -> 1.5GB scratch, 6x slow.
// qkv/proj stay at (256,2).  Tile experiments refuted: 256x128/8w qkv (r20,
// +24us, longer vmcnt drain), vectorized epilogue (r17, lane-stride breaks
// wave coalescing), 2-strip waves (r9/r13, spill), 8-wave attn (r14, L2).

#define B_  4
#define T_  2048
#define D_  1024
#define H_  16
#define HD_ 64
#define M_  (B_ * T_)   // 8192 rows

typedef short bf16x8 __attribute__((ext_vector_type(8)));
typedef float f32x4  __attribute__((ext_vector_type(4)));
typedef float f32x16 __attribute__((ext_vector_type(16)));

__device__ __forceinline__ f32x4 mfma16(bf16x8 a, bf16x8 b, f32x4 c) {
    return __builtin_amdgcn_mfma_f32_16x16x32_bf16(a, b, c, 0, 0, 0);
}
__device__ __forceinline__ f32x16 mfma32(bf16x8 a, bf16x8 b, f32x16 c) {
    return __builtin_amdgcn_mfma_f32_32x32x16_bf16(a, b, c, 0, 0, 0);
}

__device__ __forceinline__ void gl_lds16(const unsigned short* g, unsigned short* l) {
    __builtin_amdgcn_global_load_lds(
        (const __attribute__((address_space(1))) void*)g,
        (__attribute__((address_space(3))) void*)l, 16, 0, 0);
}

__device__ __forceinline__ unsigned short f2bf(float f) {
    union { __hip_bfloat16 h; unsigned short u; } cv;
    cv.h = __float2bfloat16(f);
    return cv.u;
}
__device__ __forceinline__ float bf2f(unsigned short u) {
    return __uint_as_float(((unsigned)u) << 16);
}
__device__ __forceinline__ float exp2_fast(float x) {
    return __builtin_amdgcn_exp2f(x);   // v_exp_f32: 2^x
}

struct su4 { unsigned short x, y, z, w; };

// ---------------------------------------------------------------------------
// Single fp32->bf16 conversion kernel for x + all 4 weights.
// ---------------------------------------------------------------------------
__global__ __launch_bounds__(256)
void cvt_all_kernel(const float* __restrict__ x,
                    const float* __restrict__ Wq, const float* __restrict__ Wk,
                    const float* __restrict__ Wv, const float* __restrict__ Wp,
                    unsigned short* __restrict__ dst) {
    const int i = blockIdx.x * 256 + threadIdx.x;   // float4 index, < 3145728
    const float* src;
    int j;
    if (i < 2097152) {                              // x: 8388608 elems / 4
        src = x; j = i;
    } else {
        const int k = i - 2097152;
        const int wsel = k >> 18;                   // 262144 float4 per weight
        j = k & 262143;
        src = (wsel == 0) ? Wq : (wsel == 1) ? Wk : (wsel == 2) ? Wv : Wp;
    }
    const float4 v = ((const float4*)src)[j];
    su4 o;
    o.x = f2bf(v.x); o.y = f2bf(v.y); o.z = f2bf(v.z); o.w = f2bf(v.w);
    ((su4*)dst)[i] = o;
}

// ---------------------------------------------------------------------------
// Fused QKV GEMM (verified, 79us): 128x128 tile, 4 waves.  C = X @ W^T.
// Q,K -> [B,H,T,HD]; V -> [B,H,HD,T] via operand-swapped MFMA.  Epilogue:
// per instruction, 16 lanes write 16 contiguous 2B values - coalesced.
// ---------------------------------------------------------------------------
__global__ __launch_bounds__(256, 2)
void qkv_kernel(const unsigned short* __restrict__ X,
                const unsigned short* __restrict__ Wq,
                const unsigned short* __restrict__ Wk,
                const unsigned short* __restrict__ Wv,
                unsigned short* __restrict__ Qo,
                unsigned short* __restrict__ Ko,
                unsigned short* __restrict__ Vo)
{
    __shared__ unsigned short As[128 * 64];
    __shared__ unsigned short Bs[128 * 64];

    const int m0 = blockIdx.x * 128;
    const int by = blockIdx.y;
    const unsigned short* W = (by < 8) ? Wq : (by < 16) ? Wk : Wv;
    unsigned short*       O = (by < 8) ? Qo : (by < 16) ? Ko : Vo;
    const int n0   = (by & 7) * 128;
    const bool vsec = (by >= 16);
    const int tid  = threadIdx.x;
    const int lane = tid & 63;
    const int wv   = tid >> 6;
    const int wr   = (wv >> 1) * 64;
    const int wc   = (wv & 1) * 64;
    const int g    = lane >> 4;
    const int c    = lane & 15;

    f32x4 acc[4][4] = {};

    for (int k0 = 0; k0 < D_; k0 += 64) {
        #pragma unroll
        for (int i = 0; i < 4; ++i) {
            const int flat = i * 2048 + tid * 8;
            const int row = flat >> 6, col = flat & 63;
            gl_lds16(X + (size_t)(m0 + row) * D_ + k0 + col, As + flat);
            gl_lds16(W + (size_t)(n0 + row) * D_ + k0 + col, Bs + flat);
        }
        __syncthreads();
        #pragma unroll
        for (int kk = 0; kk < 64; kk += 32) {
            bf16x8 af[4], bg[4];
            #pragma unroll
            for (int mi = 0; mi < 4; ++mi)
                af[mi] = *(const bf16x8*)(As + (wr + mi * 16 + c) * 64 + kk + g * 8);
            #pragma unroll
            for (int ni = 0; ni < 4; ++ni)
                bg[ni] = *(const bf16x8*)(Bs + (wc + ni * 16 + c) * 64 + kk + g * 8);
            if (!vsec) {
                #pragma unroll
                for (int mi = 0; mi < 4; ++mi)
                    #pragma unroll
                    for (int ni = 0; ni < 4; ++ni)
                        acc[mi][ni] = mfma16(af[mi], bg[ni], acc[mi][ni]);
            } else {
                #pragma unroll
                for (int mi = 0; mi < 4; ++mi)
                    #pragma unroll
                    for (int ni = 0; ni < 4; ++ni)
                        acc[mi][ni] = mfma16(bg[ni], af[mi], acc[mi][ni]);
            }
        }
        __syncthreads();
    }

    if (!vsec) {
        #pragma unroll
        for (int mi = 0; mi < 4; ++mi)
            #pragma unroll
            for (int ni = 0; ni < 4; ++ni)
                #pragma unroll
                for (int r = 0; r < 4; ++r) {
                    const int m = m0 + wr + mi * 16 + g * 4 + r;
                    const int n = n0 + wc + ni * 16 + c;
                    const int b = m >> 11, t = m & (T_ - 1);
                    const int h = n >> 6,  hd = n & 63;
                    O[((size_t)((b << 4) + h) * T_ + t) * HD_ + hd] = f2bf(acc[mi][ni][r]);
                }
    } else {
        #pragma unroll
        for (int mi = 0; mi < 4; ++mi)
            #pragma unroll
            for (int ni = 0; ni < 4; ++ni)
                #pragma unroll
                for (int r = 0; r < 4; ++r) {
                    const int n = n0 + wc + ni * 16 + g * 4 + r;
                    const int m = m0 + wr + mi * 16 + c;
                    const int b = m >> 11, t = m & (T_ - 1);
                    const int h = n >> 6,  hd = n & 63;
                    O[((size_t)((b << 4) + h) * HD_ + hd) * T_ + t] = f2bf(acc[mi][ni][r]);
                }
    }
}

// ---------------------------------------------------------------------------
// Causal flash attention (r16 verified): 32x32 MFMA, 4 waves x 32 q-rows =
// 128 rows per block.  Grid (64 bh, 16 q-tiles) LPT.  Double-buffered LDS,
// 3-bit XOR swizzle, defer-max, setprio.
// ---------------------------------------------------------------------------
__global__ __launch_bounds__(256, 4)
void attn_kernel(const unsigned short* __restrict__ Q,
                 const unsigned short* __restrict__ K,
                 const unsigned short* __restrict__ VT,
                 unsigned short* __restrict__ Y)
{
    __shared__ unsigned short Ks[2][4096];   // K tiles, swizzled
    __shared__ unsigned short Vs[2][4096];   // V^T tiles, swizzled

    const int bh = blockIdx.x;          // fast axis -> XCD panel residency
    const int qt = 15 - blockIdx.y;     // LPT: heaviest q-tiles first
    const unsigned short* Qp  = Q  + (size_t)bh * T_ * HD_;
    const unsigned short* Kp  = K  + (size_t)bh * T_ * HD_;
    const unsigned short* VTp = VT + (size_t)bh * HD_ * T_;
    const int b = bh >> 4, h = bh & 15;

    const int tid  = threadIdx.x;
    const int lane = tid & 63;
    const int w    = tid >> 6;          // wave 0..3
    const int hi   = lane >> 5;         // lane half
    const int q31  = lane & 31;
    const float SC = 0.18033688011112042f;   // (1/sqrt(64)) * log2(e)

    const int qw = qt * 128 + w * 32;   // wave's q base (32 rows)
    const int nt = 2 * qt + 2;          // 64-key tiles (even)

    // Staging constants (3-bit swizzle involution)
    int srow[2], scol[2];
    #pragma unroll
    for (int i = 0; i < 2; ++i) {
        const int L = (i * 256 + tid) * 16;
        srow[i] = L >> 7;                                   // 0..63
        scol[i] = (L & 127) ^ ((srow[i] & 7) << 4);         // pre-swizzled src col (bytes)
    }

    // Q as B-operand frags: col q = q31, k(d) = dstep*16 + hi*8 + j; pre-scaled
    bf16x8 qf[4];
    #pragma unroll
    for (int dstep = 0; dstep < 4; ++dstep) {
        bf16x8 t = *(const bf16x8*)(Qp + (size_t)(qw + q31) * HD_ + dstep * 16 + hi * 8);
        #pragma unroll
        for (int j = 0; j < 8; ++j)
            t[j] = (short)f2bf(bf2f((unsigned short)t[j]) * SC);
        qf[dstep] = t;
    }

    float m_l = -1e30f, l_l = 0.f;
    f32x16 o0 = {}, o1 = {};            // O^T: d-halves 0..31 / 32..63, col q
    const int swz = (lane & 7) << 4;    // read swizzle (read rows ≡ lane&7 mod 8)

    auto stage = [&](int buf, int tb) {
        #pragma unroll
        for (int i = 0; i < 2; ++i) {
            const int L = (i * 256 + tid) * 16;
            gl_lds16(Kp + (size_t)(tb + srow[i]) * HD_ + (scol[i] >> 1),
                     &Ks[buf][L >> 1]);
            gl_lds16(VTp + (size_t)srow[i] * T_ + tb + (scol[i] >> 1),
                     &Vs[buf][L >> 1]);
        }
    };

    auto compute = [&](const unsigned short* Kbuf, const unsigned short* Vbuf, int tb) {
        if (tb > qw + 31) return;       // wave fully masked
        const char* Kb = (const char*)Kbuf;
        const char* Vb = (const char*)Vbuf;

        __builtin_amdgcn_s_setprio(1);

        // ---- QK^T (swapped): s0 = keys tb..tb+31, s1 = tb+32..tb+63
        f32x16 s0 = {}, s1 = {};
        #pragma unroll
        for (int dstep = 0; dstep < 4; ++dstep) {
            const int col = (dstep * 32 + hi * 16) ^ swz;
            const bf16x8 kA = *(const bf16x8*)(Kb + q31 * 128 + col);
            const bf16x8 kB = *(const bf16x8*)(Kb + (32 + q31) * 128 + col);
            s0 = mfma32(kA, qf[dstep], s0);
            s1 = mfma32(kB, qf[dstep], s1);
        }

        // ---- causal mask (diagonal zone): key row = (r&3)+8*(r>>2)+4*hi
        if (tb + 63 > qw) {
            const int qq = qw + q31;
            #pragma unroll
            for (int r = 0; r < 16; ++r) {
                const int key = tb + (r & 3) + 8 * (r >> 2) + 4 * hi;
                s0[r] = (key      <= qq) ? s0[r] : -1e30f;
                s1[r] = (key + 32 <= qq) ? s1[r] : -1e30f;
            }
        }

        // ---- online softmax: per-lane 32 vals (one q) + 1 shuffle
        float pmax = s0[0];
        #pragma unroll
        for (int r = 1; r < 16; ++r) pmax = fmaxf(pmax, s0[r]);
        #pragma unroll
        for (int r = 0; r < 16; ++r) pmax = fmaxf(pmax, s1[r]);
        pmax = fmaxf(pmax, __shfl_xor(pmax, 32));

        const bool skip = __all(pmax - m_l <= 8.0f);
        float al = 1.f;
        if (!skip) {
            const float mn = fmaxf(m_l, pmax);
            al = exp2_fast(m_l - mn);
            m_l = mn;
        }

        float rs = 0.f;
        #pragma unroll
        for (int r = 0; r < 16; ++r) {
            const float e0 = exp2_fast(s0[r] - m_l);
            const float e1 = exp2_fast(s1[r] - m_l);
            s0[r] = e0; s1[r] = e1;
            rs += e0 + e1;
        }
        rs += __shfl_xor(rs, 32);
        l_l = l_l * al + rs;

        // ---- pack P into 4-reg groups (2 u32 each), exchange lane<->lane+32
        unsigned Glo0[4], Ghi0[4], Glo1[4], Ghi1[4];
        #pragma unroll
        for (int m = 0; m < 4; ++m) {
            Glo0[m] = (unsigned)f2bf(s0[4*m])   | ((unsigned)f2bf(s0[4*m+1]) << 16);
            Ghi0[m] = (unsigned)f2bf(s0[4*m+2]) | ((unsigned)f2bf(s0[4*m+3]) << 16);
            Glo1[m] = (unsigned)f2bf(s1[4*m])   | ((unsigned)f2bf(s1[4*m+1]) << 16);
            Ghi1[m] = (unsigned)f2bf(s1[4*m+2]) | ((unsigned)f2bf(s1[4*m+3]) << 16);
        }
        unsigned PGlo0[4], PGhi0[4], PGlo1[4], PGhi1[4];
        #pragma unroll
        for (int m = 0; m < 4; ++m) {
            PGlo0[m] = (unsigned)__shfl_xor((int)Glo0[m], 32);
            PGhi0[m] = (unsigned)__shfl_xor((int)Ghi0[m], 32);
            PGlo1[m] = (unsigned)__shfl_xor((int)Glo1[m], 32);
            PGhi1[m] = (unsigned)__shfl_xor((int)Ghi1[m], 32);
        }

        // ---- assemble PV B-frags: pf[ks], k = ks*16 + hi*8 + j
        bf16x8 pf[4];
        #pragma unroll
        for (int ks = 0; ks < 4; ++ks) {
            const int m0i = 2 * (ks & 1);
            const int m1i = m0i + 1;
            const unsigned gl0 = (ks < 2) ? Glo0[m0i] : Glo1[m0i];
            const unsigned gh0 = (ks < 2) ? Ghi0[m0i] : Ghi1[m0i];
            const unsigned gl1 = (ks < 2) ? Glo0[m1i] : Glo1[m1i];
            const unsigned gh1 = (ks < 2) ? Ghi0[m1i] : Ghi1[m1i];
            const unsigned pl0 = (ks < 2) ? PGlo0[m0i] : PGlo1[m0i];
            const unsigned ph0 = (ks < 2) ? PGhi0[m0i] : PGhi1[m0i];
            const unsigned pl1 = (ks < 2) ? PGlo0[m1i] : PGlo1[m1i];
            const unsigned ph1 = (ks < 2) ? PGhi0[m1i] : PGhi1[m1i];
            union { unsigned u[4]; bf16x8 v; } pp;
            pp.u[0] = hi ? pl1 : gl0;
            pp.u[1] = hi ? ph1 : gh0;
            pp.u[2] = hi ? gl1 : pl0;
            pp.u[3] = hi ? gh1 : ph0;
            pf[ks] = pp.v;
        }

        // ---- rescale (skipped when deferred) + PV
        if (!skip) {
            #pragma unroll
            for (int r = 0; r < 16; ++r) { o0[r] *= al; o1[r] *= al; }
        }
        #pragma unroll
        for (int ks = 0; ks < 4; ++ks) {
            const int col = (ks * 32 + hi * 16) ^ swz;
            const bf16x8 vA = *(const bf16x8*)(Vb + q31 * 128 + col);
            const bf16x8 vB = *(const bf16x8*)(Vb + (32 + q31) * 128 + col);
            o0 = mfma32(vA, pf[ks], o0);
            o1 = mfma32(vB, pf[ks], o1);
        }

        __builtin_amdgcn_s_setprio(0);
    };

    // 2x double-buffer pipeline (nt even)
    stage(0, 0);
    __syncthreads();
    for (int ti = 0; ti < nt; ti += 2) {
        stage(1, (ti + 1) << 6);
        compute(Ks[0], Vs[0], ti << 6);
        __syncthreads();
        if (ti + 2 < nt) stage(0, (ti + 2) << 6);
        compute(Ks[1], Vs[1], (ti + 1) << 6);
        __syncthreads();
    }

    // ---- epilogue: O[q = qw+q31][d = dhalf*32 + 8t + 4hi + e], uint2 stores
    const float li = 1.f / l_l;
    const size_t rowoff = (size_t)(b * T_ + qw + q31) * D_ + h * 64;
    #pragma unroll
    for (int t = 0; t < 4; ++t) {
        uint2 st0, st1;
        st0.x = (unsigned)f2bf(o0[4*t]   * li) | ((unsigned)f2bf(o0[4*t+1] * li) << 16);
        st0.y = (unsigned)f2bf(o0[4*t+2] * li) | ((unsigned)f2bf(o0[4*t+3] * li) << 16);
        st1.x = (unsigned)f2bf(o1[4*t]   * li) | ((unsigned)f2bf(o1[4*t+1] * li) << 16);
        st1.y = (unsigned)f2bf(o1[4*t+2] * li) | ((unsigned)f2bf(o1[4*t+3] * li) << 16);
        *(uint2*)(Y + rowoff      + 8 * t + 4 * hi) = st0;
        *(uint2*)(Y + rowoff + 32 + 8 * t + 4 * hi) = st1;
    }
}

// ---------------------------------------------------------------------------
// Output projection:  out = Y @ Wp^T + bp.  Y bf16[8192,1024]; out fp32.
// KEEP (256,2): (256,4) would cap VGPR at 64 -> spill (r17/r18 trap).
// ---------------------------------------------------------------------------
__global__ __launch_bounds__(256, 2)
void proj_kernel(const unsigned short* __restrict__ Yin,
                 const unsigned short* __restrict__ Wp,
                 const float* __restrict__ bp,
                 float* __restrict__ Out)
{
    __shared__ unsigned short As[128 * 64];
    __shared__ unsigned short Bs[128 * 64];

    const int m0 = blockIdx.x * 128;
    const int n0 = blockIdx.y * 128;
    const int tid  = threadIdx.x;
    const int lane = tid & 63;
    const int wv   = tid >> 6;
    const int wr   = (wv >> 1) * 64;
    const int wc   = (wv & 1) * 64;
    const int g    = lane >> 4;
    const int c    = lane & 15;

    f32x4 acc[4][4] = {};

    for (int k0 = 0; k0 < D_; k0 += 64) {
        #pragma unroll
        for (int i = 0; i < 4; ++i) {
            const int flat = i * 2048 + tid * 8;
            const int row = flat >> 6, col = flat & 63;
            gl_lds16(Yin + (size_t)(m0 + row) * D_ + k0 + col, As + flat);
            gl_lds16(Wp  + (size_t)(n0 + row) * D_ + k0 + col, Bs + flat);
        }
        __syncthreads();
        #pragma unroll
        for (int kk = 0; kk < 64; kk += 32) {
            bf16x8 af[4], bg[4];
            #pragma unroll
            for (int mi = 0; mi < 4; ++mi)
                af[mi] = *(const bf16x8*)(As + (wr + mi * 16 + c) * 64 + kk + g * 8);
            #pragma unroll
            for (int ni = 0; ni < 4; ++ni)
                bg[ni] = *(const bf16x8*)(Bs + (wc + ni * 16 + c) * 64 + kk + g * 8);
            #pragma unroll
            for (int mi = 0; mi < 4; ++mi)
                #pragma unroll
                for (int ni = 0; ni < 4; ++ni)
                    acc[mi][ni] = mfma16(af[mi], bg[ni], acc[mi][ni]);
        }
        __syncthreads();
    }

    #pragma unroll
    for (int mi = 0; mi < 4; ++mi) {
        #pragma unroll
        for (int ni = 0; ni < 4; ++ni) {
            const int n = n0 + wc + ni * 16 + c;
            const float bb = bp[n];
            #pragma unroll
            for (int r = 0; r < 4; ++r) {
                const int m = m0 + wr + mi * 16 + g * 4 + r;
                Out[(size_t)m * D_ + n] = acc[mi][ni][r] + bb;
            }
        }
    }
}

// ---------------------------------------------------------------------------
extern "C" void kernel_launch(void* const* d_in, const int* in_sizes, int n_in,
                              void* d_out, int out_size, void* d_ws, size_t ws_size,
                              hipStream_t stream) {
    const float* x  = (const float*)d_in[0];
    const float* Wq = (const float*)d_in[1];
    const float* Wk = (const float*)d_in[2];
    const float* Wv = (const float*)d_in[3];
    const float* Wp = (const float*)d_in[4];
    const float* bp = (const float*)d_in[5];
    float* out = (float*)d_out;

    const size_t SZ  = (size_t)M_ * D_;      // 8388608
    const size_t WSZ = (size_t)D_ * D_;      // 1048576
    unsigned short* ws = (unsigned short*)d_ws;
    unsigned short* XB  = ws;                 // also Y after qkv
    unsigned short* WQB = XB  + SZ;
    unsigned short* WKB = WQB + WSZ;
    unsigned short* WVB = WKB + WSZ;
    unsigned short* WPB = WVB + WSZ;
    unsigned short* Qw  = WPB + WSZ;
    unsigned short* Kw  = Qw + SZ;
    unsigned short* Vw  = Kw + SZ;            // V^T [B,H,HD,T]
    unsigned short* Yw  = XB;                 // overlay: x_bf16 dead after qkv

    dim3 blk(256);
    cvt_all_kernel<<<dim3(12288), blk, 0, stream>>>(x, Wq, Wk, Wv, Wp, ws);

    qkv_kernel <<<dim3(M_ / 128, 24), blk, 0, stream>>>(XB, WQB, WKB, WVB, Qw, Kw, Vw);
    attn_kernel<<<dim3(B_ * H_, 16), blk, 0, stream>>>(Qw, Kw, Vw, Yw);
    proj_kernel<<<dim3(M_ / 128, D_ / 128), blk, 0, stream>>>(Yw, WPB, bp, out);
}